// Round 2
// baseline (1255.790 us; speedup 1.0000x reference)
//
#include <hip/hip_runtime.h>
#include <cstdint>
#include <cstddef>

using u16 = unsigned short;
using u32 = unsigned int;

__device__ __forceinline__ float bf2f(u16 b) { union { u32 i; float f; } v; v.i = ((u32)b) << 16; return v.f; }
__device__ __forceinline__ u16 f2bf(float f) { __bf16 b = (__bf16)f; return __builtin_bit_cast(u16, b); }

// load element i from an external (input) tensor whose dtype is runtime-flagged
__device__ __forceinline__ float loadx(const void* p, size_t i, int flag_bf16) {
    return flag_bf16 ? bf2f(((const u16*)p)[i]) : ((const float*)p)[i];
}
__device__ __forceinline__ void storex(void* p, size_t i, float v, int flag_bf16) {
    if (flag_bf16) ((u16*)p)[i] = f2bf(v);
    else           ((float*)p)[i] = v;
}

// ---------------- dtype detection ----------------
// bf16 data: low u16 of each u32 is a bf16 of ~N(0,1) -> exponent bits in [100,145] always.
// f32 data: low u16 is random mantissa bits -> exponent field uniform over 0..255 (~18% hit).
__global__ void k_detect(const u32* __restrict__ x, int* __restrict__ flag) {
    int lane = threadIdx.x;
    u32 u = x[lane];
    int e = (u >> 7) & 0xFF;
    int hit = (e >= 100 && e <= 145) ? 1 : 0;
    unsigned long long b = __ballot(hit);
    if (lane == 0) flag[0] = (__popcll(b) >= 32) ? 1 : 0;
}

// ---------------- weight conversion to f32 arena ----------------
struct ConvJob { const void* src; float* dst; int n; };
struct ConvJobs { ConvJob j[12]; };

__global__ void k_wconv(ConvJobs jobs, const int* __restrict__ flagp) {
    const int f = *flagp;
    const int stride = gridDim.x * blockDim.x;
    for (int s = 0; s < 12; ++s) {
        const ConvJob jb = jobs.j[s];
        for (int i = blockIdx.x * blockDim.x + threadIdx.x; i < jb.n; i += stride)
            jb.dst[i] = loadx(jb.src, i, f);
    }
}

// ---------------- graph preprocessing ----------------
__global__ void k_count(const int* __restrict__ col, int* __restrict__ deg, int E) {
    int e = blockIdx.x * 256 + threadIdx.x;
    if (e < E) atomicAdd(&deg[col[e]], 1);
}

__global__ void k_dinv(const int* __restrict__ deg, float* __restrict__ dinv, int N) {
    int i = blockIdx.x * 256 + threadIdx.x;
    if (i < N) dinv[i] = rsqrtf((float)(deg[i] + 1));  // +1 self loop
}

__global__ __launch_bounds__(1024) void k_scan(const int* __restrict__ deg, int* __restrict__ rowptr, int N) {
    __shared__ int sh[1024];
    __shared__ int carry;
    const int tid = threadIdx.x;
    if (tid == 0) carry = 0;
    __syncthreads();
    for (int base = 0; base < N; base += 1024) {
        int i = base + tid;
        int v = (i < N) ? deg[i] : 0;
        sh[tid] = v;
        __syncthreads();
        for (int off = 1; off < 1024; off <<= 1) {
            int t = (tid >= off) ? sh[tid - off] : 0;
            __syncthreads();
            sh[tid] += t;
            __syncthreads();
        }
        if (i < N) rowptr[i] = carry + sh[tid] - v;  // exclusive
        __syncthreads();
        if (tid == 0) carry += sh[1023];
        __syncthreads();
    }
    if (tid == 0) rowptr[N] = carry;
}

__global__ void k_fill(const int* __restrict__ row, const int* __restrict__ col,
                       const int* __restrict__ rowptr, int* __restrict__ cursor,
                       int* __restrict__ csr_src, int E) {
    int e = blockIdx.x * 256 + threadIdx.x;
    if (e >= E) return;
    int d = col[e];
    int pos = atomicAdd(&cursor[d], 1);
    csr_src[rowptr[d] + pos] = row[e];
}

// ---------------- f32 GEMM: out[M,NC] = A[M,K] @ W[K,NC] (+bias)(+relu)(+l2norm) ----------------
// W is f32 [K,NC] row-major (pre-converted). A: internal f32, or external (flag dtype).
// Block: 256 threads, 32 rows. c = tid&(NC-1), rg = tid/NC; thread owns rows j*G+rg.

template <int K, int NC, bool A_EXT, bool BIAS, bool RELU, bool NORM, bool OUT_EXT>
__global__ __launch_bounds__(256) void k_gemm(const void* __restrict__ Av, const float* __restrict__ W,
                                              const float* __restrict__ bias, void* __restrict__ outv,
                                              size_t out_off, int M, const int* __restrict__ flagp) {
    constexpr int G = 256 / NC;   // 2 (NC=128) or 4 (NC=64)
    constexpr int RPT = 32 / G;   // 16 or 8
    constexpr int KC = 64;        // k-chunk staged in LDS
    __shared__ float sW[KC * NC];
    __shared__ float sA[32][KC + 1];
    const int flag = *flagp;
    const int tid = threadIdx.x;
    const int c = tid & (NC - 1);
    const int rg = tid / NC;
    const int r0 = blockIdx.x * 32;

    float acc[RPT];
#pragma unroll
    for (int j = 0; j < RPT; ++j) acc[j] = 0.f;

    for (int kc = 0; kc < K; kc += KC) {
        __syncthreads();
        for (int i = tid; i < KC * NC; i += 256) sW[i] = W[(size_t)kc * NC + i];
        for (int i = tid; i < 32 * KC; i += 256) {
            int rr = i / KC, kk = i - rr * KC;
            int grow = r0 + rr;
            if (grow > M - 1) grow = M - 1;
            size_t aidx = (size_t)grow * K + kc + kk;
            float av = A_EXT ? loadx(Av, aidx, flag) : ((const float*)Av)[aidx];
            sA[rr][kk] = av;
        }
        __syncthreads();
        for (int k = 0; k < KC; ++k) {
            float w = sW[k * NC + c];
#pragma unroll
            for (int j = 0; j < RPT; ++j)
                acc[j] += sA[j * G + rg][k] * w;
        }
    }

    float bv = BIAS ? bias[c] : 0.f;
#pragma unroll
    for (int j = 0; j < RPT; ++j) {
        float v = acc[j] + bv;
        if (RELU) v = fmaxf(v, 0.f);
        acc[j] = v;
    }

    if constexpr (NORM) {  // only instantiated with NC=128 (G=2)
        __shared__ float red[4][RPT];
        const int wave = tid >> 6;
        const int lane = tid & 63;
#pragma unroll
        for (int j = 0; j < RPT; ++j) {
            float s = acc[j] * acc[j];
#pragma unroll
            for (int m = 1; m < 64; m <<= 1) s += __shfl_xor(s, m, 64);
            if (lane == 0) red[wave][j] = s;
        }
        __syncthreads();
#pragma unroll
        for (int j = 0; j < RPT; ++j) {
            float ss = red[rg * 2][j] + red[rg * 2 + 1][j];
            float inv = 1.f / fmaxf(sqrtf(ss), 1e-12f);
            acc[j] *= inv;
        }
    }

#pragma unroll
    for (int j = 0; j < RPT; ++j) {
        int r = r0 + j * G + rg;
        if (r < M) {
            size_t oi = out_off + (size_t)r * NC + c;
            if (OUT_EXT) storex(outv, oi, acc[j], flag);
            else         ((float*)outv)[oi] = acc[j];
        }
    }
}

// ---------------- GCN aggregation (f32): out[n] = relu( sum_s h[s]*dinv[s]*dinv[n] + h[n]*dinv[n]^2 + b ) ----
template <int F>
__global__ __launch_bounds__(256) void k_agg(const float* __restrict__ h, const int* __restrict__ rowptr,
                                             const int* __restrict__ srcidx, const float* __restrict__ dinv,
                                             const float* __restrict__ bias, float* __restrict__ out, int N) {
    const int node = blockIdx.x * 4 + (threadIdx.x >> 6);
    if (node >= N) return;
    const int lane = threadIdx.x & 63;
    const float dn = dinv[node];
    int e = rowptr[node];
    const int end = rowptr[node + 1];
    if (F == 128) {
        const float2* hp = reinterpret_cast<const float2*>(h);
        float2 s = hp[(size_t)node * 64 + lane];
        float a0 = s.x * dn * dn, a1 = s.y * dn * dn;
        for (; e < end; ++e) {
            int src = srcidx[e];
            float w = dinv[src] * dn;
            float2 hv = hp[(size_t)src * 64 + lane];
            a0 += hv.x * w;
            a1 += hv.y * w;
        }
        a0 = fmaxf(a0 + bias[2 * lane], 0.f);
        a1 = fmaxf(a1 + bias[2 * lane + 1], 0.f);
        reinterpret_cast<float2*>(out)[(size_t)node * 64 + lane] = make_float2(a0, a1);
    } else {
        float a0 = h[(size_t)node * 64 + lane] * dn * dn;
        for (; e < end; ++e) {
            int src = srcidx[e];
            a0 += h[(size_t)src * 64 + lane] * (dinv[src] * dn);
        }
        a0 = fmaxf(a0 + bias[lane], 0.f);
        out[(size_t)node * 64 + lane] = a0;
    }
}

// ---------------- cluster head: softmax(v @ Wc2 + bc2), v[N,64] f32, Wc2 f32 [64,3] ----------------
__global__ __launch_bounds__(256) void k_clus(const float* __restrict__ v, const float* __restrict__ Wc2,
                                              const float* __restrict__ bc2, void* __restrict__ outv,
                                              size_t out_off, int N, const int* __restrict__ flagp) {
    const int node = blockIdx.x * 4 + (threadIdx.x >> 6);
    if (node >= N) return;
    const int flag = *flagp;
    const int lane = threadIdx.x & 63;
    float ul = v[(size_t)node * 64 + lane];
    float a0 = ul * Wc2[lane * 3 + 0];
    float a1 = ul * Wc2[lane * 3 + 1];
    float a2 = ul * Wc2[lane * 3 + 2];
#pragma unroll
    for (int m = 1; m < 64; m <<= 1) {
        a0 += __shfl_xor(a0, m, 64);
        a1 += __shfl_xor(a1, m, 64);
        a2 += __shfl_xor(a2, m, 64);
    }
    a0 += bc2[0];
    a1 += bc2[1];
    a2 += bc2[2];
    float mx = fmaxf(a0, fmaxf(a1, a2));
    float e0 = expf(a0 - mx), e1 = expf(a1 - mx), e2 = expf(a2 - mx);
    float inv = 1.f / (e0 + e1 + e2);
    if (lane < 3) {
        float r = (lane == 0) ? e0 : ((lane == 1) ? e1 : e2);
        storex(outv, out_off + (size_t)node * 3 + lane, r * inv, flag);
    }
}

// ---------------- launcher ----------------
extern "C" void kernel_launch(void* const* d_in, const int* in_sizes, int n_in,
                              void* d_out, int out_size, void* d_ws, size_t ws_size,
                              hipStream_t stream) {
    const int N = in_sizes[0] / 128;   // 50000
    const int E = in_sizes[1] / 2;     // 800000
    const void* x[2] = {d_in[0], d_in[2]};
    const int* ei[2] = {(const int*)d_in[1], (const int*)d_in[3]};

    size_t off = 0;
    auto alloc = [&](size_t bytes) -> void* {
        void* p = (char*)d_ws + off;
        off += (bytes + 255) & ~(size_t)255;
        return p;
    };
    int* flag = (int*)alloc(256);
    // f32 weight arena
    const int wcnt[12] = {128 * 128, 128, 128 * 64, 64, 64 * 64, 64, 64 * 128, 128, 64 * 64, 64, 64 * 3, 3};
    float* wf[12];
    for (int i = 0; i < 12; ++i) wf[i] = (float*)alloc((size_t)wcnt[i] * 4);
    float* W1f = wf[0]; float* b1f = wf[1]; float* W2f = wf[2]; float* b2f = wf[3];
    float* Wp1f = wf[4]; float* bp1f = wf[5]; float* Wp2f = wf[6]; float* bp2f = wf[7];
    float* Wc1f = wf[8]; float* bc1f = wf[9]; float* Wc2f = wf[10]; float* bc2f = wf[11];

    int* deg    = (int*)alloc((size_t)2 * N * 4);
    int* cursor = deg + N;
    int* rowptr = (int*)alloc((size_t)(N + 1) * 4);
    int* csr    = (int*)alloc((size_t)E * 4);
    float* dinv = (float*)alloc((size_t)N * 4);
    float* P = (float*)alloc((size_t)N * 128 * 4);
    float* Q = (float*)alloc((size_t)N * 128 * 4);
    float* R = (float*)alloc((size_t)N * 64 * 4);
    (void)ws_size; (void)n_in; (void)out_size;

    k_detect<<<1, 64, 0, stream>>>((const u32*)d_in[0], flag);

    ConvJobs jobs;
    for (int i = 0; i < 12; ++i) jobs.j[i] = ConvJob{d_in[4 + i], wf[i], wcnt[i]};
    k_wconv<<<64, 256, 0, stream>>>(jobs, flag);

    const int gE = (E + 255) / 256, gN = (N + 255) / 256;
    const int gT = (N + 31) / 32;      // gemm blocks (32 rows each)
    const int gA = (N + 3) / 4;        // agg/clus blocks (4 nodes each)

    for (int g = 0; g < 2; ++g) {
        const int* row = ei[g];
        const int* col = ei[g] + E;
        hipMemsetAsync(deg, 0, (size_t)2 * N * 4, stream);
        k_count<<<gE, 256, 0, stream>>>(col, deg, E);
        k_dinv<<<gN, 256, 0, stream>>>(deg, dinv, N);
        k_scan<<<1, 1024, 0, stream>>>(deg, rowptr, N);
        k_fill<<<gE, 256, 0, stream>>>(row, col, rowptr, cursor, csr, E);

        // layer 1: P = x@W1 ; Q = relu(agg(P) + b1)
        k_gemm<128, 128, true, false, false, false, false><<<gT, 256, 0, stream>>>(x[g], W1f, nullptr, P, 0, N, flag);
        k_agg<128><<<gA, 256, 0, stream>>>(P, rowptr, csr, dinv, b1f, Q, N);
        // layer 2: R = Q@W2 ; P[:,:64] = z = relu(agg(R) + b2)
        k_gemm<128, 64, false, false, false, false, false><<<gT, 256, 0, stream>>>(Q, W2f, nullptr, R, 0, N, flag);
        k_agg<64><<<gA, 256, 0, stream>>>(R, rowptr, csr, dinv, b2f, P, N);

        // instance head: out_z = l2norm(relu(z@Wp1+bp1)@Wp2+bp2)
        k_gemm<64, 64, false, true, true, false, false><<<gT, 256, 0, stream>>>(P, Wp1f, bp1f, Q, 0, N, flag);
        k_gemm<64, 128, false, true, false, true, true><<<gT, 256, 0, stream>>>(Q, Wp2f, bp2f, d_out,
                                                                                (size_t)g * N * 128, N, flag);
        // cluster head: out_c = softmax(relu(z@Wc1+bc1)@Wc2+bc2)
        k_gemm<64, 64, false, true, true, false, false><<<gT, 256, 0, stream>>>(P, Wc1f, bc1f, R, 0, N, flag);
        k_clus<<<gA, 256, 0, stream>>>(R, Wc2f, bc2f, d_out,
                                       (size_t)2 * N * 128 + (size_t)g * N * 3, N, flag);
    }
}

// Round 3
// 849.627 us; speedup vs baseline: 1.4780x; 1.4780x over previous
//
#include <hip/hip_runtime.h>
#include <cstdint>
#include <cstddef>

using u16 = unsigned short;
using u32 = unsigned int;

__device__ __forceinline__ float bf2f(u16 b) { union { u32 i; float f; } v; v.i = ((u32)b) << 16; return v.f; }
__device__ __forceinline__ u16 f2bf(float f) { __bf16 b = (__bf16)f; return __builtin_bit_cast(u16, b); }
__device__ __forceinline__ float bflo(u32 u) { union { u32 i; float f; } v; v.i = u << 16; return v.f; }
__device__ __forceinline__ float bfhi(u32 u) { union { u32 i; float f; } v; v.i = u & 0xffff0000u; return v.f; }
__device__ __forceinline__ u32 pack2(float a, float b) { return (u32)f2bf(a) | ((u32)f2bf(b) << 16); }

__device__ __forceinline__ float loadx(const void* p, size_t i, int flag_bf16) {
    return flag_bf16 ? bf2f(((const u16*)p)[i]) : ((const float*)p)[i];
}
__device__ __forceinline__ void storex(void* p, size_t i, float v, int flag_bf16) {
    if (flag_bf16) ((u16*)p)[i] = f2bf(v);
    else           ((float*)p)[i] = v;
}

// ---------------- dtype detection (kept for robustness; r2 proved f32 mode) ----------------
__global__ void k_detect(const u32* __restrict__ x, int* __restrict__ flag) {
    int lane = threadIdx.x;
    u32 u = x[lane];
    int e = (u >> 7) & 0xFF;
    int hit = (e >= 100 && e <= 145) ? 1 : 0;
    unsigned long long b = __ballot(hit);
    if (lane == 0) flag[0] = (__popcll(b) >= 32) ? 1 : 0;
}

// ---------------- weight conversion to f32 arena ----------------
struct ConvJob { const void* src; float* dst; int n; };
struct ConvJobs { ConvJob j[12]; };

__global__ void k_wconv(ConvJobs jobs, const int* __restrict__ flagp) {
    const int f = *flagp;
    const int stride = gridDim.x * blockDim.x;
    for (int s = 0; s < 12; ++s) {
        const ConvJob jb = jobs.j[s];
        for (int i = blockIdx.x * blockDim.x + threadIdx.x; i < jb.n; i += stride)
            jb.dst[i] = loadx(jb.src, i, f);
    }
}

// ---------------- graph preprocessing (gridDim.y = graph id) ----------------
__global__ void k_count(const int* __restrict__ ei0, const int* __restrict__ ei1,
                        int* __restrict__ deg, int N, int E) {
    const int g = blockIdx.y;
    const int* col = (g ? ei1 : ei0) + E;
    int e = blockIdx.x * 256 + threadIdx.x;
    if (e < E) atomicAdd(&deg[g * N + col[e]], 1);
}

__global__ void k_dinv(const int* __restrict__ deg, float* __restrict__ dinv, int N) {
    const int g = blockIdx.y;
    int i = blockIdx.x * 256 + threadIdx.x;
    if (i < N) dinv[g * N + i] = rsqrtf((float)(deg[g * N + i] + 1));  // +1 self loop
}

// hierarchical scan: part sums -> top scan -> write
__global__ __launch_bounds__(256) void k_scan_part(const int* __restrict__ deg, int* __restrict__ part,
                                                   int N, int nchunk) {
    const int g = blockIdx.y, b = blockIdx.x, tid = threadIdx.x;
    const int lane = tid & 63, wave = tid >> 6;
    const int* d = deg + (size_t)g * N;
    int i0 = b * 1024 + tid * 4;
    int s = 0;
#pragma unroll
    for (int k = 0; k < 4; ++k) if (i0 + k < N) s += d[i0 + k];
#pragma unroll
    for (int m = 1; m < 64; m <<= 1) s += __shfl_xor(s, m, 64);
    __shared__ int wt[4];
    if (lane == 0) wt[wave] = s;
    __syncthreads();
    if (tid == 0) part[g * nchunk + b] = wt[0] + wt[1] + wt[2] + wt[3];
}

__global__ void k_scan_top(int* __restrict__ part, int* __restrict__ rowptr, int N, int nchunk) {
    const int g = threadIdx.x >> 6;
    const int lane = threadIdx.x & 63;
    int orig = (lane < nchunk) ? part[g * nchunk + lane] : 0;
    int v = orig;
#pragma unroll
    for (int off = 1; off < 64; off <<= 1) {
        int t = __shfl_up(v, off, 64);
        if (lane >= off) v += t;
    }
    if (lane < nchunk) part[g * nchunk + lane] = v - orig;  // exclusive
    if (lane == 63) rowptr[(size_t)g * (N + 1) + N] = v;    // total = E
}

__global__ __launch_bounds__(256) void k_scan_write(const int* __restrict__ deg, const int* __restrict__ part,
                                                    int* __restrict__ rowptr, int N, int nchunk) {
    const int g = blockIdx.y, b = blockIdx.x, tid = threadIdx.x;
    const int lane = tid & 63, wave = tid >> 6;
    const int* d = deg + (size_t)g * N;
    int i0 = b * 1024 + tid * 4;
    int v[4]; int s = 0;
#pragma unroll
    for (int k = 0; k < 4; ++k) { v[k] = (i0 + k < N) ? d[i0 + k] : 0; s += v[k]; }
    int inc = s;
#pragma unroll
    for (int off = 1; off < 64; off <<= 1) {
        int t = __shfl_up(inc, off, 64);
        if (lane >= off) inc += t;
    }
    __shared__ int wt[4];
    if (lane == 63) wt[wave] = inc;
    __syncthreads();
    int woff = 0;
    for (int w = 0; w < wave; ++w) woff += wt[w];
    int run = inc - s + woff + part[g * nchunk + b];
    int* rp = rowptr + (size_t)g * (N + 1);
#pragma unroll
    for (int k = 0; k < 4; ++k) {
        if (i0 + k < N) rp[i0 + k] = run;
        run += v[k];
    }
}

// fill CSR with (src, weight) pairs; weight = dinv[s]*dinv[d] precomputed
__global__ void k_fill(const int* __restrict__ ei0, const int* __restrict__ ei1,
                       const int* __restrict__ rowptr, int* __restrict__ cursor,
                       const float* __restrict__ dinv, int2* __restrict__ csrw, int N, int E) {
    const int g = blockIdx.y;
    const int* ei = g ? ei1 : ei0;
    int e = blockIdx.x * 256 + threadIdx.x;
    if (e >= E) return;
    int s = ei[e];
    int d = ei[E + e];
    int pos = atomicAdd(&cursor[g * N + d], 1);
    float w = dinv[g * N + s] * dinv[g * N + d];
    csrw[(size_t)g * E + rowptr[(size_t)g * (N + 1) + d] + pos] = make_int2(s, __float_as_int(w));
}

// ---------------- f32 GEMM: out[M,NC] = A[M,K] @ W[K,NC] (+bias)(+relu)(+l2norm) ----------------
// AM: 0=f32 internal, 1=bf16 internal, 2=external (flag dtype). OM: 0=f32, 1=bf16, 2=external.
template <int K, int NC, int AM, bool BIAS, bool RELU, bool NORM, int OM>
__global__ __launch_bounds__(256) void k_gemm(const void* __restrict__ A0, const void* __restrict__ A1,
                                              size_t astride, const float* __restrict__ W,
                                              const float* __restrict__ bias, void* __restrict__ outv,
                                              size_t out_off, size_t ostride, int M,
                                              const int* __restrict__ flagp) {
    constexpr int G = 256 / NC;   // 2 (NC=128) or 4 (NC=64)
    constexpr int RPT = 32 / G;   // 16 or 8
    constexpr int KC = 64;
    __shared__ float sW[KC * NC];
    __shared__ float sA[32][KC + 1];
    const int flag = *flagp;
    const int gph = blockIdx.y;
    const void* Av = gph ? A1 : A0;
    const size_t abase = (size_t)gph * astride;
    const size_t obase = out_off + (size_t)gph * ostride;
    const int tid = threadIdx.x;
    const int c = tid & (NC - 1);
    const int rg = tid / NC;
    const int r0 = blockIdx.x * 32;

    float acc[RPT];
#pragma unroll
    for (int j = 0; j < RPT; ++j) acc[j] = 0.f;

    for (int kc = 0; kc < K; kc += KC) {
        __syncthreads();
        for (int i = tid; i < KC * NC; i += 256) sW[i] = W[(size_t)kc * NC + i];
        for (int i = tid; i < 32 * KC; i += 256) {
            int rr = i / KC, kk = i - rr * KC;
            int grow = r0 + rr;
            if (grow > M - 1) grow = M - 1;
            size_t aidx = abase + (size_t)grow * K + kc + kk;
            float av;
            if (AM == 2)      av = loadx(Av, aidx, flag);
            else if (AM == 1) av = bf2f(((const u16*)Av)[aidx]);
            else              av = ((const float*)Av)[aidx];
            sA[rr][kk] = av;
        }
        __syncthreads();
        for (int k = 0; k < KC; ++k) {
            float w = sW[k * NC + c];
#pragma unroll
            for (int j = 0; j < RPT; ++j)
                acc[j] += sA[j * G + rg][k] * w;
        }
    }

    float bv = BIAS ? bias[c] : 0.f;
#pragma unroll
    for (int j = 0; j < RPT; ++j) {
        float v = acc[j] + bv;
        if (RELU) v = fmaxf(v, 0.f);
        acc[j] = v;
    }

    if constexpr (NORM) {  // only NC=128 (G=2)
        __shared__ float red[4][RPT];
        const int wave = tid >> 6;
        const int lane = tid & 63;
#pragma unroll
        for (int j = 0; j < RPT; ++j) {
            float s = acc[j] * acc[j];
#pragma unroll
            for (int m = 1; m < 64; m <<= 1) s += __shfl_xor(s, m, 64);
            if (lane == 0) red[wave][j] = s;
        }
        __syncthreads();
#pragma unroll
        for (int j = 0; j < RPT; ++j) {
            float ss = red[rg * 2][j] + red[rg * 2 + 1][j];
            acc[j] *= 1.f / fmaxf(sqrtf(ss), 1e-12f);
        }
    }

#pragma unroll
    for (int j = 0; j < RPT; ++j) {
        int r = r0 + j * G + rg;
        if (r < M) {
            size_t oi = obase + (size_t)r * NC + c;
            if (OM == 2)      storex(outv, oi, acc[j], flag);
            else if (OM == 1) ((u16*)outv)[oi] = f2bf(acc[j]);
            else              ((float*)outv)[oi] = acc[j];
        }
    }
}

// ---------------- GCN aggregation, bf16 rows, precomputed edge weights ----------------
// F=128: h rows are 64 u32 (bf16x2) per node. out bf16. wave per node.
__global__ __launch_bounds__(256) void k_agg128(const u32* __restrict__ H, const int* __restrict__ rowptr,
                                                const int2* __restrict__ csrw, const float* __restrict__ dinv,
                                                const float* __restrict__ bias, u32* __restrict__ out,
                                                int N, int E) {
    const int g = blockIdx.y;
    const int node = blockIdx.x * 4 + (threadIdx.x >> 6);
    if (node >= N) return;
    const int lane = threadIdx.x & 63;
    const u32* h = H + (size_t)g * N * 64;
    const int* rp = rowptr + (size_t)g * (N + 1);
    const int2* cw = csrw + (size_t)g * E;
    const float dn = dinv[g * N + node];
    int e = rp[node];
    const int end = rp[node + 1];
    u32 su = h[(size_t)node * 64 + lane];
    float w = dn * dn;
    float a0 = bflo(su) * w, a1 = bfhi(su) * w;
    while (e + 2 <= end) {
        int2 c0 = cw[e], c1 = cw[e + 1];
        float w0 = __int_as_float(c0.y), w1 = __int_as_float(c1.y);
        u32 h0 = h[(size_t)c0.x * 64 + lane];
        u32 h1 = h[(size_t)c1.x * 64 + lane];
        a0 += bflo(h0) * w0; a1 += bfhi(h0) * w0;
        a0 += bflo(h1) * w1; a1 += bfhi(h1) * w1;
        e += 2;
    }
    if (e < end) {
        int2 c0 = cw[e];
        float w0 = __int_as_float(c0.y);
        u32 h0 = h[(size_t)c0.x * 64 + lane];
        a0 += bflo(h0) * w0; a1 += bfhi(h0) * w0;
    }
    a0 = fmaxf(a0 + bias[2 * lane], 0.f);
    a1 = fmaxf(a1 + bias[2 * lane + 1], 0.f);
    out[((size_t)g * N + node) * 64 + lane] = pack2(a0, a1);
}

// F=64: h rows are 64 u16 per node. out f32.
__global__ __launch_bounds__(256) void k_agg64(const u16* __restrict__ H, const int* __restrict__ rowptr,
                                               const int2* __restrict__ csrw, const float* __restrict__ dinv,
                                               const float* __restrict__ bias, float* __restrict__ out,
                                               int N, int E) {
    const int g = blockIdx.y;
    const int node = blockIdx.x * 4 + (threadIdx.x >> 6);
    if (node >= N) return;
    const int lane = threadIdx.x & 63;
    const u16* h = H + (size_t)g * N * 64;
    const int* rp = rowptr + (size_t)g * (N + 1);
    const int2* cw = csrw + (size_t)g * E;
    const float dn = dinv[g * N + node];
    int e = rp[node];
    const int end = rp[node + 1];
    float a0 = bf2f(h[(size_t)node * 64 + lane]) * dn * dn;
    while (e + 2 <= end) {
        int2 c0 = cw[e], c1 = cw[e + 1];
        float w0 = __int_as_float(c0.y), w1 = __int_as_float(c1.y);
        float h0 = bf2f(h[(size_t)c0.x * 64 + lane]);
        float h1 = bf2f(h[(size_t)c1.x * 64 + lane]);
        a0 += h0 * w0 + h1 * w1;
        e += 2;
    }
    if (e < end) {
        int2 c0 = cw[e];
        a0 += bf2f(h[(size_t)c0.x * 64 + lane]) * __int_as_float(c0.y);
    }
    a0 = fmaxf(a0 + bias[lane], 0.f);
    out[((size_t)g * N + node) * 64 + lane] = a0;
}

// ---------------- cluster head: softmax(v @ Wc2 + bc2), v[N,64] f32 ----------------
__global__ __launch_bounds__(256) void k_clus(const float* __restrict__ v, const float* __restrict__ Wc2,
                                              const float* __restrict__ bc2, void* __restrict__ outv,
                                              size_t out_off, size_t ostride, int N,
                                              const int* __restrict__ flagp) {
    const int g = blockIdx.y;
    const int node = blockIdx.x * 4 + (threadIdx.x >> 6);
    if (node >= N) return;
    const int flag = *flagp;
    const int lane = threadIdx.x & 63;
    float ul = v[((size_t)g * N + node) * 64 + lane];
    float a0 = ul * Wc2[lane * 3 + 0];
    float a1 = ul * Wc2[lane * 3 + 1];
    float a2 = ul * Wc2[lane * 3 + 2];
#pragma unroll
    for (int m = 1; m < 64; m <<= 1) {
        a0 += __shfl_xor(a0, m, 64);
        a1 += __shfl_xor(a1, m, 64);
        a2 += __shfl_xor(a2, m, 64);
    }
    a0 += bc2[0]; a1 += bc2[1]; a2 += bc2[2];
    float mx = fmaxf(a0, fmaxf(a1, a2));
    float e0 = expf(a0 - mx), e1 = expf(a1 - mx), e2 = expf(a2 - mx);
    float inv = 1.f / (e0 + e1 + e2);
    if (lane < 3) {
        float r = (lane == 0) ? e0 : ((lane == 1) ? e1 : e2);
        storex(outv, out_off + (size_t)g * ostride + (size_t)node * 3 + lane, r * inv, flag);
    }
}

// ---------------- launcher ----------------
extern "C" void kernel_launch(void* const* d_in, const int* in_sizes, int n_in,
                              void* d_out, int out_size, void* d_ws, size_t ws_size,
                              hipStream_t stream) {
    const int N = in_sizes[0] / 128;   // 50000
    const int E = in_sizes[1] / 2;     // 800000
    const int* ei0 = (const int*)d_in[1];
    const int* ei1 = (const int*)d_in[3];

    size_t off = 0;
    auto alloc = [&](size_t bytes) -> void* {
        void* p = (char*)d_ws + off;
        off += (bytes + 255) & ~(size_t)255;
        return p;
    };
    int* flag = (int*)alloc(256);
    const int wcnt[12] = {128 * 128, 128, 128 * 64, 64, 64 * 64, 64, 64 * 128, 128, 64 * 64, 64, 64 * 3, 3};
    float* wf[12];
    for (int i = 0; i < 12; ++i) wf[i] = (float*)alloc((size_t)wcnt[i] * 4);
    float* W1f = wf[0];  float* b1f = wf[1];  float* W2f = wf[2];  float* b2f = wf[3];
    float* Wp1f = wf[4]; float* bp1f = wf[5]; float* Wp2f = wf[6]; float* bp2f = wf[7];
    float* Wc1f = wf[8]; float* bc1f = wf[9]; float* Wc2f = wf[10]; float* bc2f = wf[11];

    int* deg    = (int*)alloc((size_t)4 * N * 4);      // [2][N] deg + [2][N] cursor
    int* cursor = deg + 2 * N;
    int* rowptr = (int*)alloc((size_t)2 * (N + 1) * 4);
    int* part   = (int*)alloc(128 * 4);
    float* dinv = (float*)alloc((size_t)2 * N * 4);
    int2* csrw  = (int2*)alloc((size_t)2 * E * 8);
    u16* A1 = (u16*)alloc((size_t)2 * N * 128 * 2);    // gemm1 out (bf16); H2 aliases
    u16* H2 = A1;                                      // gemm2 out (bf16), alias after agg128
    u16* Qb = (u16*)alloc((size_t)2 * N * 128 * 2);    // agg1 out (bf16); U/V alias
    float* U = (float*)Qb;                             // head hidden (f32), alias after gemm2
    float* Z = (float*)alloc((size_t)2 * N * 64 * 4);  // agg2 out (f32)
    (void)ws_size; (void)n_in; (void)out_size;

    k_detect<<<1, 64, 0, stream>>>((const u32*)d_in[0], flag);
    ConvJobs jobs;
    for (int i = 0; i < 12; ++i) jobs.j[i] = ConvJob{d_in[4 + i], wf[i], wcnt[i]};
    k_wconv<<<64, 256, 0, stream>>>(jobs, flag);

    const int nchunk = (N + 1023) / 1024;
    const dim3 gE((E + 255) / 256, 2), gN((N + 255) / 256, 2);
    const dim3 gS(nchunk, 2);
    const dim3 gT((N + 31) / 32, 2);
    const dim3 gA((N + 3) / 4, 2);

    hipMemsetAsync(deg, 0, (size_t)4 * N * 4, stream);
    k_count<<<gE, 256, 0, stream>>>(ei0, ei1, deg, N, E);
    k_dinv<<<gN, 256, 0, stream>>>(deg, dinv, N);
    k_scan_part<<<gS, 256, 0, stream>>>(deg, part, N, nchunk);
    k_scan_top<<<1, 128, 0, stream>>>(part, rowptr, N, nchunk);
    k_scan_write<<<gS, 256, 0, stream>>>(deg, part, rowptr, N, nchunk);
    k_fill<<<gE, 256, 0, stream>>>(ei0, ei1, rowptr, cursor, dinv, csrw, N, E);

    // layer 1: A1 = x @ W1 (bf16) ; Qb = relu(agg(A1) + b1) (bf16)
    k_gemm<128, 128, 2, false, false, false, 1><<<gT, 256, 0, stream>>>(
        d_in[0], d_in[2], 0, W1f, nullptr, A1, 0, (size_t)N * 128, N, flag);
    k_agg128<<<gA, 256, 0, stream>>>((const u32*)A1, rowptr, csrw, dinv, b1f, (u32*)Qb, N, E);
    // layer 2: H2 = Qb @ W2 (bf16) ; Z = relu(agg(H2) + b2) (f32)
    k_gemm<128, 64, 1, false, false, false, 1><<<gT, 256, 0, stream>>>(
        Qb, Qb, (size_t)N * 128, W2f, nullptr, H2, 0, (size_t)N * 64, N, flag);
    k_agg64<<<gA, 256, 0, stream>>>(H2, rowptr, csrw, dinv, b2f, Z, N, E);

    // instance head: out_z = l2norm(relu(Z@Wp1+bp1)@Wp2+bp2)
    k_gemm<64, 64, 0, true, true, false, 0><<<gT, 256, 0, stream>>>(
        Z, Z, (size_t)N * 64, Wp1f, bp1f, U, 0, (size_t)N * 64, N, flag);
    k_gemm<64, 128, 0, true, false, true, 2><<<gT, 256, 0, stream>>>(
        U, U, (size_t)N * 64, Wp2f, bp2f, d_out, 0, (size_t)N * 128, N, flag);
    // cluster head: out_c = softmax(relu(Z@Wc1+bc1)@Wc2+bc2)  (V reuses U region)
    k_gemm<64, 64, 0, true, true, false, 0><<<gT, 256, 0, stream>>>(
        Z, Z, (size_t)N * 64, Wc1f, bc1f, U, 0, (size_t)N * 64, N, flag);
    k_clus<<<gA, 256, 0, stream>>>(U, Wc2f, bc2f, d_out,
                                   (size_t)2 * N * 128, (size_t)N * 3, N, flag);
}

// Round 4
// 595.054 us; speedup vs baseline: 2.1104x; 1.4278x over previous
//
#include <hip/hip_runtime.h>
#include <cstdint>
#include <cstddef>

using u16 = unsigned short;
using u32 = unsigned int;

typedef __bf16 bf16x8 __attribute__((ext_vector_type(8)));
typedef float  f32x4  __attribute__((ext_vector_type(4)));

__device__ __forceinline__ float bf2f(u16 b) { union { u32 i; float f; } v; v.i = ((u32)b) << 16; return v.f; }
__device__ __forceinline__ u16 f2bf(float f) { __bf16 b = (__bf16)f; return __builtin_bit_cast(u16, b); }
__device__ __forceinline__ float bflo(u32 u) { union { u32 i; float f; } v; v.i = u << 16; return v.f; }
__device__ __forceinline__ float bfhi(u32 u) { union { u32 i; float f; } v; v.i = u & 0xffff0000u; return v.f; }
__device__ __forceinline__ u32 pack2(float a, float b) { return (u32)f2bf(a) | ((u32)f2bf(b) << 16); }

__device__ __forceinline__ float loadx(const void* p, size_t i, int flag_bf16) {
    return flag_bf16 ? bf2f(((const u16*)p)[i]) : ((const float*)p)[i];
}
__device__ __forceinline__ void storex(void* p, size_t i, float v, int flag_bf16) {
    if (flag_bf16) ((u16*)p)[i] = f2bf(v);
    else           ((float*)p)[i] = v;
}

// A-fragment loader: 8 contiguous K-elements, external (flagged) or internal bf16
__device__ __forceinline__ bf16x8 load_afrag_ext(const void* A, size_t off, int flag) {
    if (flag) return *reinterpret_cast<const bf16x8*>((const u16*)A + off);
    const float* f = (const float*)A + off;
    float4 a = *reinterpret_cast<const float4*>(f);
    float4 b = *reinterpret_cast<const float4*>(f + 4);
    bf16x8 r;
    r[0] = (__bf16)a.x; r[1] = (__bf16)a.y; r[2] = (__bf16)a.z; r[3] = (__bf16)a.w;
    r[4] = (__bf16)b.x; r[5] = (__bf16)b.y; r[6] = (__bf16)b.z; r[7] = (__bf16)b.w;
    return r;
}

// ---------------- dtype detection ----------------
__global__ void k_detect(const u32* __restrict__ x, int* __restrict__ flag) {
    int lane = threadIdx.x;
    u32 u = x[lane];
    int e = (u >> 7) & 0xFF;
    int hit = (e >= 100 && e <= 145) ? 1 : 0;
    unsigned long long b = __ballot(hit);
    if (lane == 0) flag[0] = (__popcll(b) >= 32) ? 1 : 0;
}

// ---------------- weight conversion: external -> f32 arena ----------------
struct ConvJob { const void* src; float* dst; int n; };
struct ConvJobs { ConvJob j[12]; };

__global__ void k_wconv(ConvJobs jobs, const int* __restrict__ flagp) {
    const int f = *flagp;
    const int stride = gridDim.x * blockDim.x;
    for (int s = 0; s < 12; ++s) {
        const ConvJob jb = jobs.j[s];
        for (int i = blockIdx.x * blockDim.x + threadIdx.x; i < jb.n; i += stride)
            jb.dst[i] = loadx(jb.src, i, f);
    }
}

// f32 arena [K][NC] -> bf16 transposed [NC][K]
struct TJob { const float* W; u16* WT; int K, NC; };
struct TJobs { TJob j[5]; };

__global__ void k_wtrans(TJobs jobs) {
    const int stride = gridDim.x * blockDim.x;
    for (int s = 0; s < 5; ++s) {
        const TJob jb = jobs.j[s];
        const int tot = jb.K * jb.NC;
        for (int i = blockIdx.x * blockDim.x + threadIdx.x; i < tot; i += stride) {
            int k = i / jb.NC, n = i - k * jb.NC;
            jb.WT[n * jb.K + k] = f2bf(jb.W[i]);
        }
    }
}

// ---------------- graph preprocessing (gridDim.y = graph id) ----------------
__global__ void k_count(const int* __restrict__ ei0, const int* __restrict__ ei1,
                        int* __restrict__ deg, int N, int E) {
    const int g = blockIdx.y;
    const int* col = (g ? ei1 : ei0) + E;
    int e = blockIdx.x * 256 + threadIdx.x;
    if (e < E) atomicAdd(&deg[g * N + col[e]], 1);
}

__global__ void k_dinv(const int* __restrict__ deg, float* __restrict__ dinv, int N) {
    const int g = blockIdx.y;
    int i = blockIdx.x * 256 + threadIdx.x;
    if (i < N) dinv[g * N + i] = rsqrtf((float)(deg[g * N + i] + 1));  // +1 self loop
}

__global__ __launch_bounds__(256) void k_scan_part(const int* __restrict__ deg, int* __restrict__ part,
                                                   int N, int nchunk) {
    const int g = blockIdx.y, b = blockIdx.x, tid = threadIdx.x;
    const int lane = tid & 63, wave = tid >> 6;
    const int* d = deg + (size_t)g * N;
    int i0 = b * 1024 + tid * 4;
    int s = 0;
#pragma unroll
    for (int k = 0; k < 4; ++k) if (i0 + k < N) s += d[i0 + k];
#pragma unroll
    for (int m = 1; m < 64; m <<= 1) s += __shfl_xor(s, m, 64);
    __shared__ int wt[4];
    if (lane == 0) wt[wave] = s;
    __syncthreads();
    if (tid == 0) part[g * nchunk + b] = wt[0] + wt[1] + wt[2] + wt[3];
}

__global__ void k_scan_top(int* __restrict__ part, int* __restrict__ rowptr, int N, int nchunk) {
    const int g = threadIdx.x >> 6;
    const int lane = threadIdx.x & 63;
    int orig = (lane < nchunk) ? part[g * nchunk + lane] : 0;
    int v = orig;
#pragma unroll
    for (int off = 1; off < 64; off <<= 1) {
        int t = __shfl_up(v, off, 64);
        if (lane >= off) v += t;
    }
    if (lane < nchunk) part[g * nchunk + lane] = v - orig;  // exclusive
    if (lane == 63) rowptr[(size_t)g * (N + 1) + N] = v;
}

__global__ __launch_bounds__(256) void k_scan_write(const int* __restrict__ deg, const int* __restrict__ part,
                                                    int* __restrict__ rowptr, int N, int nchunk) {
    const int g = blockIdx.y, b = blockIdx.x, tid = threadIdx.x;
    const int lane = tid & 63, wave = tid >> 6;
    const int* d = deg + (size_t)g * N;
    int i0 = b * 1024 + tid * 4;
    int v[4]; int s = 0;
#pragma unroll
    for (int k = 0; k < 4; ++k) { v[k] = (i0 + k < N) ? d[i0 + k] : 0; s += v[k]; }
    int inc = s;
#pragma unroll
    for (int off = 1; off < 64; off <<= 1) {
        int t = __shfl_up(inc, off, 64);
        if (lane >= off) inc += t;
    }
    __shared__ int wt[4];
    if (lane == 63) wt[wave] = inc;
    __syncthreads();
    int woff = 0;
    for (int w = 0; w < wave; ++w) woff += wt[w];
    int run = inc - s + woff + part[g * nchunk + b];
    int* rp = rowptr + (size_t)g * (N + 1);
#pragma unroll
    for (int k = 0; k < 4; ++k) {
        if (i0 + k < N) rp[i0 + k] = run;
        run += v[k];
    }
}

__global__ void k_fill(const int* __restrict__ ei0, const int* __restrict__ ei1,
                       const int* __restrict__ rowptr, int* __restrict__ cursor,
                       const float* __restrict__ dinv, int2* __restrict__ csrw, int N, int E) {
    const int g = blockIdx.y;
    const int* ei = g ? ei1 : ei0;
    int e = blockIdx.x * 256 + threadIdx.x;
    if (e >= E) return;
    int s = ei[e];
    int d = ei[E + e];
    int pos = atomicAdd(&cursor[g * N + d], 1);
    float w = dinv[g * N + s] * dinv[g * N + d];
    csrw[(size_t)g * E + rowptr[(size_t)g * (N + 1) + d] + pos] = make_int2(s, __float_as_int(w));
}

// ---------------- MFMA GEMM: out[M,NC] = A[M,K] @ W[K,NC] (+bias)(+relu)(+l2norm) ----------------
// WT: bf16 [NC][K] row-major (L1/L2 resident). Block = 4 waves; wave = 16 rows x all NC cols.
// A fragments straight from global (each element read once per block). No LDS.
template <int K, int NC, bool AEXT, bool BIAS, bool RELU, bool NORM, bool OEXT>
__global__ __launch_bounds__(256) void k_mgemm(const void* __restrict__ A0, const void* __restrict__ A1,
                                               size_t astride, const u16* __restrict__ WT,
                                               const float* __restrict__ bias, void* __restrict__ outv,
                                               size_t out_off, size_t ostride, int M,
                                               const int* __restrict__ flagp) {
    constexpr int NT = NC / 16;
    constexpr int KI = K / 32;
    const int flag = *flagp;
    const int g = blockIdx.y;
    const void* Av = g ? A1 : A0;
    const int lane = threadIdx.x & 63;
    const int wave = threadIdx.x >> 6;
    const int q = lane >> 4;       // quad 0..3
    const int c = lane & 15;       // col-in-tile / A-row-in-tile
    const int m0 = blockIdx.x * 64 + wave * 16;
    int arow = m0 + c;
    if (arow > M - 1) arow = M - 1;           // clamp reads; stores guarded
    const size_t abase = (size_t)g * astride + (size_t)arow * K;

    // A fragments for all KI slabs
    bf16x8 afr[KI];
#pragma unroll
    for (int ki = 0; ki < KI; ++ki) {
        size_t off = abase + (size_t)ki * 32 + q * 8;
        if (AEXT) afr[ki] = load_afrag_ext(Av, off, flag);
        else      afr[ki] = *reinterpret_cast<const bf16x8*>((const u16*)Av + off);
    }

    f32x4 acc[NT];
#pragma unroll
    for (int t = 0; t < NT; ++t) acc[t] = (f32x4){0.f, 0.f, 0.f, 0.f};

#pragma unroll
    for (int ki = 0; ki < KI; ++ki) {
#pragma unroll
        for (int t = 0; t < NT; ++t) {
            const u16* bptr = WT + (size_t)(t * 16 + c) * K + ki * 32 + q * 8;
            bf16x8 bfr = *reinterpret_cast<const bf16x8*>(bptr);
            acc[t] = __builtin_amdgcn_mfma_f32_16x16x32_bf16(afr[ki], bfr, acc[t], 0, 0, 0);
        }
    }

#pragma unroll
    for (int t = 0; t < NT; ++t) {
        float bv = BIAS ? bias[t * 16 + c] : 0.f;
#pragma unroll
        for (int r = 0; r < 4; ++r) {
            float v = acc[t][r] + bv;
            if (RELU) v = fmaxf(v, 0.f);
            acc[t][r] = v;
        }
    }

    if constexpr (NORM) {
        // row m0+q*4+r spans the 16 lanes sharing q; reduce over c via xor 1,2,4,8
        float ss[4] = {0.f, 0.f, 0.f, 0.f};
#pragma unroll
        for (int t = 0; t < NT; ++t)
#pragma unroll
            for (int r = 0; r < 4; ++r) ss[r] += acc[t][r] * acc[t][r];
#pragma unroll
        for (int r = 0; r < 4; ++r) {
#pragma unroll
            for (int m = 1; m < 16; m <<= 1) ss[r] += __shfl_xor(ss[r], m, 64);
            float s = 1.f / fmaxf(sqrtf(ss[r]), 1e-12f);
#pragma unroll
            for (int t = 0; t < NT; ++t) acc[t][r] *= s;
        }
    }

    const size_t obase = out_off + (size_t)g * ostride;
#pragma unroll
    for (int r = 0; r < 4; ++r) {
        const int grow = m0 + q * 4 + r;
        if (grow < M) {
#pragma unroll
            for (int t = 0; t < NT; ++t) {
                size_t oi = obase + (size_t)grow * NC + t * 16 + c;
                if (OEXT) storex(outv, oi, acc[t][r], flag);
                else      ((u16*)outv)[oi] = f2bf(acc[t][r]);
            }
        }
    }
}

// ---------------- GCN aggregation, bf16 rows, precomputed edge weights ----------------
__global__ __launch_bounds__(256) void k_agg128(const u32* __restrict__ H, const int* __restrict__ rowptr,
                                                const int2* __restrict__ csrw, const float* __restrict__ dinv,
                                                const float* __restrict__ bias, u32* __restrict__ out,
                                                int N, int E) {
    const int g = blockIdx.y;
    const int node = blockIdx.x * 4 + (threadIdx.x >> 6);
    if (node >= N) return;
    const int lane = threadIdx.x & 63;
    const u32* h = H + (size_t)g * N * 64;
    const int* rp = rowptr + (size_t)g * (N + 1);
    const int2* cw = csrw + (size_t)g * E;
    const float dn = dinv[g * N + node];
    int e = rp[node];
    const int end = rp[node + 1];
    u32 su = h[(size_t)node * 64 + lane];
    float w = dn * dn;
    float a0 = bflo(su) * w, a1 = bfhi(su) * w;
    while (e + 2 <= end) {
        int2 c0 = cw[e], c1 = cw[e + 1];
        float w0 = __int_as_float(c0.y), w1 = __int_as_float(c1.y);
        u32 h0 = h[(size_t)c0.x * 64 + lane];
        u32 h1 = h[(size_t)c1.x * 64 + lane];
        a0 += bflo(h0) * w0; a1 += bfhi(h0) * w0;
        a0 += bflo(h1) * w1; a1 += bfhi(h1) * w1;
        e += 2;
    }
    if (e < end) {
        int2 c0 = cw[e];
        float w0 = __int_as_float(c0.y);
        u32 h0 = h[(size_t)c0.x * 64 + lane];
        a0 += bflo(h0) * w0; a1 += bfhi(h0) * w0;
    }
    a0 = fmaxf(a0 + bias[2 * lane], 0.f);
    a1 = fmaxf(a1 + bias[2 * lane + 1], 0.f);
    out[((size_t)g * N + node) * 64 + lane] = pack2(a0, a1);
}

__global__ __launch_bounds__(256) void k_agg64(const u16* __restrict__ H, const int* __restrict__ rowptr,
                                               const int2* __restrict__ csrw, const float* __restrict__ dinv,
                                               const float* __restrict__ bias, u16* __restrict__ out,
                                               int N, int E) {
    const int g = blockIdx.y;
    const int node = blockIdx.x * 4 + (threadIdx.x >> 6);
    if (node >= N) return;
    const int lane = threadIdx.x & 63;
    const u16* h = H + (size_t)g * N * 64;
    const int* rp = rowptr + (size_t)g * (N + 1);
    const int2* cw = csrw + (size_t)g * E;
    const float dn = dinv[g * N + node];
    int e = rp[node];
    const int end = rp[node + 1];
    float a0 = bf2f(h[(size_t)node * 64 + lane]) * dn * dn;
    while (e + 2 <= end) {
        int2 c0 = cw[e], c1 = cw[e + 1];
        float w0 = __int_as_float(c0.y), w1 = __int_as_float(c1.y);
        float h0 = bf2f(h[(size_t)c0.x * 64 + lane]);
        float h1 = bf2f(h[(size_t)c1.x * 64 + lane]);
        a0 += h0 * w0 + h1 * w1;
        e += 2;
    }
    if (e < end) {
        int2 c0 = cw[e];
        a0 += bf2f(h[(size_t)c0.x * 64 + lane]) * __int_as_float(c0.y);
    }
    a0 = fmaxf(a0 + bias[lane], 0.f);
    out[((size_t)g * N + node) * 64 + lane] = f2bf(a0);
}

// ---------------- cluster head: softmax(v @ Wc2 + bc2), v[N,64] bf16 ----------------
__global__ __launch_bounds__(256) void k_clus(const u16* __restrict__ v, const float* __restrict__ Wc2,
                                              const float* __restrict__ bc2, void* __restrict__ outv,
                                              size_t out_off, size_t ostride, int N,
                                              const int* __restrict__ flagp) {
    const int g = blockIdx.y;
    const int node = blockIdx.x * 4 + (threadIdx.x >> 6);
    if (node >= N) return;
    const int flag = *flagp;
    const int lane = threadIdx.x & 63;
    float ul = bf2f(v[((size_t)g * N + node) * 64 + lane]);
    float a0 = ul * Wc2[lane * 3 + 0];
    float a1 = ul * Wc2[lane * 3 + 1];
    float a2 = ul * Wc2[lane * 3 + 2];
#pragma unroll
    for (int m = 1; m < 64; m <<= 1) {
        a0 += __shfl_xor(a0, m, 64);
        a1 += __shfl_xor(a1, m, 64);
        a2 += __shfl_xor(a2, m, 64);
    }
    a0 += bc2[0]; a1 += bc2[1]; a2 += bc2[2];
    float mx = fmaxf(a0, fmaxf(a1, a2));
    float e0 = expf(a0 - mx), e1 = expf(a1 - mx), e2 = expf(a2 - mx);
    float inv = 1.f / (e0 + e1 + e2);
    if (lane < 3) {
        float r = (lane == 0) ? e0 : ((lane == 1) ? e1 : e2);
        storex(outv, out_off + (size_t)g * ostride + (size_t)node * 3 + lane, r * inv, flag);
    }
}

// ---------------- launcher ----------------
extern "C" void kernel_launch(void* const* d_in, const int* in_sizes, int n_in,
                              void* d_out, int out_size, void* d_ws, size_t ws_size,
                              hipStream_t stream) {
    const int N = in_sizes[0] / 128;   // 50000
    const int E = in_sizes[1] / 2;     // 800000
    const int* ei0 = (const int*)d_in[1];
    const int* ei1 = (const int*)d_in[3];

    size_t off = 0;
    auto alloc = [&](size_t bytes) -> void* {
        void* p = (char*)d_ws + off;
        off += (bytes + 255) & ~(size_t)255;
        return p;
    };
    int* flag = (int*)alloc(256);
    const int wcnt[12] = {128 * 128, 128, 128 * 64, 64, 64 * 64, 64, 64 * 128, 128, 64 * 64, 64, 64 * 3, 3};
    float* wf[12];
    for (int i = 0; i < 12; ++i) wf[i] = (float*)alloc((size_t)wcnt[i] * 4);
    float* b1f = wf[1]; float* b2f = wf[3]; float* bp1f = wf[5]; float* bp2f = wf[7];
    float* bc1f = wf[9]; float* Wc2f = wf[10]; float* bc2f = wf[11];
    // bf16 transposed weights [NC][K]
    u16* W1T  = (u16*)alloc(128 * 128 * 2);
    u16* W2T  = (u16*)alloc(64 * 128 * 2);
    u16* Wp1T = (u16*)alloc(64 * 64 * 2);
    u16* Wp2T = (u16*)alloc(128 * 64 * 2);
    u16* Wc1T = (u16*)alloc(64 * 64 * 2);

    int* deg    = (int*)alloc((size_t)4 * N * 4);
    int* cursor = deg + 2 * N;
    int* rowptr = (int*)alloc((size_t)2 * (N + 1) * 4);
    int* part   = (int*)alloc(128 * 4);
    float* dinv = (float*)alloc((size_t)2 * N * 4);
    int2* csrw  = (int2*)alloc((size_t)2 * E * 8);
    u16* A1 = (u16*)alloc((size_t)2 * N * 128 * 2);   // gemm1 out; H2 aliases
    u16* H2 = A1;
    u16* Qb = (u16*)alloc((size_t)2 * N * 128 * 2);   // agg1 out; U aliases
    u16* U  = Qb;
    u16* Z  = (u16*)alloc((size_t)2 * N * 64 * 2);    // agg2 out (bf16)
    (void)ws_size; (void)n_in; (void)out_size;

    k_detect<<<1, 64, 0, stream>>>((const u32*)d_in[0], flag);
    ConvJobs jobs;
    for (int i = 0; i < 12; ++i) jobs.j[i] = ConvJob{d_in[4 + i], wf[i], wcnt[i]};
    k_wconv<<<64, 256, 0, stream>>>(jobs, flag);
    TJobs tj;
    tj.j[0] = TJob{wf[0], W1T, 128, 128};
    tj.j[1] = TJob{wf[2], W2T, 128, 64};
    tj.j[2] = TJob{wf[4], Wp1T, 64, 64};
    tj.j[3] = TJob{wf[6], Wp2T, 64, 128};
    tj.j[4] = TJob{wf[8], Wc1T, 64, 64};
    k_wtrans<<<40, 256, 0, stream>>>(tj);

    const int nchunk = (N + 1023) / 1024;
    const dim3 gE((E + 255) / 256, 2), gN((N + 255) / 256, 2);
    const dim3 gS(nchunk, 2);
    const dim3 gM((N + 63) / 64, 2);
    const dim3 gA((N + 3) / 4, 2);

    hipMemsetAsync(deg, 0, (size_t)4 * N * 4, stream);
    k_count<<<gE, 256, 0, stream>>>(ei0, ei1, deg, N, E);
    k_dinv<<<gN, 256, 0, stream>>>(deg, dinv, N);
    k_scan_part<<<gS, 256, 0, stream>>>(deg, part, N, nchunk);
    k_scan_top<<<1, 128, 0, stream>>>(part, rowptr, N, nchunk);
    k_scan_write<<<gS, 256, 0, stream>>>(deg, part, rowptr, N, nchunk);
    k_fill<<<gE, 256, 0, stream>>>(ei0, ei1, rowptr, cursor, dinv, csrw, N, E);

    // layer 1: A1 = x @ W1 ; Qb = relu(agg(A1) + b1)
    k_mgemm<128, 128, true, false, false, false, false><<<gM, 256, 0, stream>>>(
        d_in[0], d_in[2], 0, W1T, nullptr, A1, 0, (size_t)N * 128, N, flag);
    k_agg128<<<gA, 256, 0, stream>>>((const u32*)A1, rowptr, csrw, dinv, b1f, (u32*)Qb, N, E);
    // layer 2: H2 = Qb @ W2 ; Z = relu(agg(H2) + b2)
    k_mgemm<128, 64, false, false, false, false, false><<<gM, 256, 0, stream>>>(
        Qb, Qb, (size_t)N * 128, W2T, nullptr, H2, 0, (size_t)N * 64, N, flag);
    k_agg64<<<gA, 256, 0, stream>>>(H2, rowptr, csrw, dinv, b2f, Z, N, E);

    // instance head: out_z = l2norm(relu(Z@Wp1+bp1)@Wp2+bp2)
    k_mgemm<64, 64, false, true, true, false, false><<<gM, 256, 0, stream>>>(
        Z, Z, (size_t)N * 64, Wp1T, bp1f, U, 0, (size_t)N * 64, N, flag);
    k_mgemm<64, 128, false, true, false, true, true><<<gM, 256, 0, stream>>>(
        U, U, (size_t)N * 64, Wp2T, bp2f, d_out, 0, (size_t)N * 128, N, flag);
    // cluster head: out_c = softmax(relu(Z@Wc1+bc1)@Wc2+bc2)
    k_mgemm<64, 64, false, true, true, false, false><<<gM, 256, 0, stream>>>(
        Z, Z, (size_t)N * 64, Wc1T, bc1f, U, 0, (size_t)N * 64, N, flag);
    k_clus<<<gA, 256, 0, stream>>>(U, Wc2f, bc2f, d_out,
                                   (size_t)2 * N * 128, (size_t)N * 3, N, flag);
}

// Round 5
// 527.869 us; speedup vs baseline: 2.3790x; 1.1273x over previous
//
#include <hip/hip_runtime.h>
#include <cstdint>
#include <cstddef>

using u16 = unsigned short;
using u32 = unsigned int;

typedef __bf16 bf16x8 __attribute__((ext_vector_type(8)));
typedef float  f32x4  __attribute__((ext_vector_type(4)));

__device__ __forceinline__ float bf2f(u16 b) { union { u32 i; float f; } v; v.i = ((u32)b) << 16; return v.f; }
__device__ __forceinline__ u16 f2bf(float f) { __bf16 b = (__bf16)f; return __builtin_bit_cast(u16, b); }
__device__ __forceinline__ float bflo(u32 u) { union { u32 i; float f; } v; v.i = u << 16; return v.f; }
__device__ __forceinline__ float bfhi(u32 u) { union { u32 i; float f; } v; v.i = u & 0xffff0000u; return v.f; }
__device__ __forceinline__ u32 pack2(float a, float b) { return (u32)f2bf(a) | ((u32)f2bf(b) << 16); }

__device__ __forceinline__ float loadx(const void* p, size_t i, int flag_bf16) {
    return flag_bf16 ? bf2f(((const u16*)p)[i]) : ((const float*)p)[i];
}
__device__ __forceinline__ void storex(void* p, size_t i, float v, int flag_bf16) {
    if (flag_bf16) ((u16*)p)[i] = f2bf(v);
    else           ((float*)p)[i] = v;
}

__device__ __forceinline__ bf16x8 load_afrag_ext(const void* A, size_t off, int flag) {
    if (flag) return *reinterpret_cast<const bf16x8*>((const u16*)A + off);
    const float* f = (const float*)A + off;
    float4 a = *reinterpret_cast<const float4*>(f);
    float4 b = *reinterpret_cast<const float4*>(f + 4);
    bf16x8 r;
    r[0] = (__bf16)a.x; r[1] = (__bf16)a.y; r[2] = (__bf16)a.z; r[3] = (__bf16)a.w;
    r[4] = (__bf16)b.x; r[5] = (__bf16)b.y; r[6] = (__bf16)b.z; r[7] = (__bf16)b.w;
    return r;
}

// ---------------- dtype detection ----------------
__global__ void k_detect(const u32* __restrict__ x, int* __restrict__ flag) {
    int lane = threadIdx.x;
    u32 u = x[lane];
    int e = (u >> 7) & 0xFF;
    int hit = (e >= 100 && e <= 145) ? 1 : 0;
    unsigned long long b = __ballot(hit);
    if (lane == 0) flag[0] = (__popcll(b) >= 32) ? 1 : 0;
}

// ---------------- weight conversion ----------------
struct ConvJob { const void* src; float* dst; int n; };
struct ConvJobs { ConvJob j[12]; };

__global__ void k_wconv(ConvJobs jobs, const int* __restrict__ flagp) {
    const int f = *flagp;
    const int stride = gridDim.x * blockDim.x;
    for (int s = 0; s < 12; ++s) {
        const ConvJob jb = jobs.j[s];
        for (int i = blockIdx.x * blockDim.x + threadIdx.x; i < jb.n; i += stride)
            jb.dst[i] = loadx(jb.src, i, f);
    }
}

struct TJob { const float* W; u16* WT; int K, NC; };
struct TJobs { TJob j[5]; };

__global__ void k_wtrans(TJobs jobs) {
    const int stride = gridDim.x * blockDim.x;
    for (int s = 0; s < 5; ++s) {
        const TJob jb = jobs.j[s];
        const int tot = jb.K * jb.NC;
        for (int i = blockIdx.x * blockDim.x + threadIdx.x; i < tot; i += stride) {
            int k = i / jb.NC, n = i - k * jb.NC;
            jb.WT[n * jb.K + k] = f2bf(jb.W[i]);
        }
    }
}

// ---------------- graph preprocessing (gridDim.y = graph id) ----------------
__global__ void k_count(const int* __restrict__ ei0, const int* __restrict__ ei1,
                        int* __restrict__ deg, int N, int E) {
    const int g = blockIdx.y;
    const int* col = (g ? ei1 : ei0) + E;
    int e = blockIdx.x * 256 + threadIdx.x;
    if (e < E) atomicAdd(&deg[g * N + col[e]], 1);
}

__global__ __launch_bounds__(256) void k_scan_part(const int* __restrict__ deg, int* __restrict__ part,
                                                   int N, int nchunk) {
    const int g = blockIdx.y, b = blockIdx.x, tid = threadIdx.x;
    const int lane = tid & 63, wave = tid >> 6;
    const int* d = deg + (size_t)g * N;
    int i0 = b * 1024 + tid * 4;
    int s = 0;
#pragma unroll
    for (int k = 0; k < 4; ++k) if (i0 + k < N) s += d[i0 + k];
#pragma unroll
    for (int m = 1; m < 64; m <<= 1) s += __shfl_xor(s, m, 64);
    __shared__ int wt[4];
    if (lane == 0) wt[wave] = s;
    __syncthreads();
    if (tid == 0) part[g * nchunk + b] = wt[0] + wt[1] + wt[2] + wt[3];
}

__global__ void k_scan_top(int* __restrict__ part, int* __restrict__ rowptr, int N, int nchunk) {
    const int g = threadIdx.x >> 6;
    const int lane = threadIdx.x & 63;
    int orig = (lane < nchunk) ? part[g * nchunk + lane] : 0;
    int v = orig;
#pragma unroll
    for (int off = 1; off < 64; off <<= 1) {
        int t = __shfl_up(v, off, 64);
        if (lane >= off) v += t;
    }
    if (lane < nchunk) part[g * nchunk + lane] = v - orig;  // exclusive
    if (lane == 63) rowptr[(size_t)g * (N + 1) + N] = v;
}

// writes rowptr, cursor (=rowptr copy for absolute-position fill), and dinv
__global__ __launch_bounds__(256) void k_scan_write(const int* __restrict__ deg, const int* __restrict__ part,
                                                    int* __restrict__ rowptr, int* __restrict__ cursor,
                                                    float* __restrict__ dinv, int N, int nchunk) {
    const int g = blockIdx.y, b = blockIdx.x, tid = threadIdx.x;
    const int lane = tid & 63, wave = tid >> 6;
    const int* d = deg + (size_t)g * N;
    int i0 = b * 1024 + tid * 4;
    int v[4]; int s = 0;
#pragma unroll
    for (int k = 0; k < 4; ++k) { v[k] = (i0 + k < N) ? d[i0 + k] : 0; s += v[k]; }
    int inc = s;
#pragma unroll
    for (int off = 1; off < 64; off <<= 1) {
        int t = __shfl_up(inc, off, 64);
        if (lane >= off) inc += t;
    }
    __shared__ int wt[4];
    if (lane == 63) wt[wave] = inc;
    __syncthreads();
    int woff = 0;
    for (int w = 0; w < wave; ++w) woff += wt[w];
    int run = inc - s + woff + part[g * nchunk + b];
    int* rp = rowptr + (size_t)g * (N + 1);
    int* cur = cursor + (size_t)g * N;
    float* dv = dinv + (size_t)g * N;
#pragma unroll
    for (int k = 0; k < 4; ++k) {
        int i = i0 + k;
        if (i < N) {
            rp[i] = run;
            cur[i] = run;
            dv[i] = rsqrtf((float)(v[k] + 1));  // +1 self loop
        }
        run += v[k];
    }
}

// fill CSR with (src, weight); cursor holds absolute positions
__global__ void k_fill(const int* __restrict__ ei0, const int* __restrict__ ei1,
                       int* __restrict__ cursor, const float* __restrict__ dinv,
                       int2* __restrict__ csrw, int N, int E) {
    const int g = blockIdx.y;
    const int* ei = g ? ei1 : ei0;
    int e = blockIdx.x * 256 + threadIdx.x;
    if (e >= E) return;
    int s = ei[e];
    int d = ei[E + e];
    int pos = atomicAdd(&cursor[g * N + d], 1);
    float w = dinv[g * N + s] * dinv[g * N + d];
    csrw[(size_t)g * E + pos] = make_int2(s, __float_as_int(w));
}

// ---------------- MFMA GEMM ----------------
template <int K, int NC, bool AEXT, bool BIAS, bool RELU, bool NORM, bool OEXT>
__global__ __launch_bounds__(256) void k_mgemm(const void* __restrict__ A0, const void* __restrict__ A1,
                                               size_t astride, const u16* __restrict__ WT,
                                               const float* __restrict__ bias, void* __restrict__ outv,
                                               size_t out_off, size_t ostride, int M,
                                               const int* __restrict__ flagp) {
    constexpr int NT = NC / 16;
    constexpr int KI = K / 32;
    const int flag = *flagp;
    const int g = blockIdx.y;
    const void* Av = g ? A1 : A0;
    const int lane = threadIdx.x & 63;
    const int wave = threadIdx.x >> 6;
    const int q = lane >> 4;
    const int c = lane & 15;
    const int m0 = blockIdx.x * 64 + wave * 16;
    int arow = m0 + c;
    if (arow > M - 1) arow = M - 1;
    const size_t abase = (size_t)g * astride + (size_t)arow * K;

    bf16x8 afr[KI];
#pragma unroll
    for (int ki = 0; ki < KI; ++ki) {
        size_t off = abase + (size_t)ki * 32 + q * 8;
        if (AEXT) afr[ki] = load_afrag_ext(Av, off, flag);
        else      afr[ki] = *reinterpret_cast<const bf16x8*>((const u16*)Av + off);
    }

    f32x4 acc[NT];
#pragma unroll
    for (int t = 0; t < NT; ++t) acc[t] = (f32x4){0.f, 0.f, 0.f, 0.f};

#pragma unroll
    for (int ki = 0; ki < KI; ++ki) {
#pragma unroll
        for (int t = 0; t < NT; ++t) {
            const u16* bptr = WT + (size_t)(t * 16 + c) * K + ki * 32 + q * 8;
            bf16x8 bfr = *reinterpret_cast<const bf16x8*>(bptr);
            acc[t] = __builtin_amdgcn_mfma_f32_16x16x32_bf16(afr[ki], bfr, acc[t], 0, 0, 0);
        }
    }

#pragma unroll
    for (int t = 0; t < NT; ++t) {
        float bv = BIAS ? bias[t * 16 + c] : 0.f;
#pragma unroll
        for (int r = 0; r < 4; ++r) {
            float v = acc[t][r] + bv;
            if (RELU) v = fmaxf(v, 0.f);
            acc[t][r] = v;
        }
    }

    if constexpr (NORM) {
        float ss[4] = {0.f, 0.f, 0.f, 0.f};
#pragma unroll
        for (int t = 0; t < NT; ++t)
#pragma unroll
            for (int r = 0; r < 4; ++r) ss[r] += acc[t][r] * acc[t][r];
#pragma unroll
        for (int r = 0; r < 4; ++r) {
#pragma unroll
            for (int m = 1; m < 16; m <<= 1) ss[r] += __shfl_xor(ss[r], m, 64);
            float s = 1.f / fmaxf(sqrtf(ss[r]), 1e-12f);
#pragma unroll
            for (int t = 0; t < NT; ++t) acc[t][r] *= s;
        }
    }

    const size_t obase = out_off + (size_t)g * ostride;
#pragma unroll
    for (int r = 0; r < 4; ++r) {
        const int grow = m0 + q * 4 + r;
        if (grow < M) {
#pragma unroll
            for (int t = 0; t < NT; ++t) {
                size_t oi = obase + (size_t)grow * NC + t * 16 + c;
                if (OEXT) storex(outv, oi, acc[t][r], flag);
                else      ((u16*)outv)[oi] = f2bf(acc[t][r]);
            }
        }
    }
}

// ---------------- GCN aggregation, deep-MLP unroll-8 ----------------
__global__ __launch_bounds__(256) void k_agg128(const u32* __restrict__ H, const int* __restrict__ rowptr,
                                                const int2* __restrict__ csrw, const float* __restrict__ dinv,
                                                const float* __restrict__ bias, u32* __restrict__ out,
                                                int N, int E) {
    const int g = blockIdx.y;
    const int node = blockIdx.x * 4 + (threadIdx.x >> 6);
    if (node >= N) return;
    const int lane = threadIdx.x & 63;
    const u32* h = H + (size_t)g * N * 64;
    const int* rp = rowptr + (size_t)g * (N + 1);
    const int2* cw = csrw + (size_t)g * E;
    const float dn = dinv[g * N + node];
    int e = rp[node];
    const int end = rp[node + 1];
    u32 su = h[(size_t)node * 64 + lane];
    float w = dn * dn;
    float a0 = bflo(su) * w, a1 = bfhi(su) * w;
    while (e + 8 <= end) {
        int2 c[8];
#pragma unroll
        for (int j = 0; j < 8; ++j) c[j] = cw[e + j];
        u32 hv[8];
#pragma unroll
        for (int j = 0; j < 8; ++j) hv[j] = h[(size_t)c[j].x * 64 + lane];
#pragma unroll
        for (int j = 0; j < 8; ++j) {
            float wj = __int_as_float(c[j].y);
            a0 += bflo(hv[j]) * wj;
            a1 += bfhi(hv[j]) * wj;
        }
        e += 8;
    }
    while (e + 2 <= end) {
        int2 c0 = cw[e], c1 = cw[e + 1];
        u32 h0 = h[(size_t)c0.x * 64 + lane];
        u32 h1 = h[(size_t)c1.x * 64 + lane];
        float w0 = __int_as_float(c0.y), w1 = __int_as_float(c1.y);
        a0 += bflo(h0) * w0; a1 += bfhi(h0) * w0;
        a0 += bflo(h1) * w1; a1 += bfhi(h1) * w1;
        e += 2;
    }
    if (e < end) {
        int2 c0 = cw[e];
        float w0 = __int_as_float(c0.y);
        u32 h0 = h[(size_t)c0.x * 64 + lane];
        a0 += bflo(h0) * w0; a1 += bfhi(h0) * w0;
    }
    a0 = fmaxf(a0 + bias[2 * lane], 0.f);
    a1 = fmaxf(a1 + bias[2 * lane + 1], 0.f);
    out[((size_t)g * N + node) * 64 + lane] = pack2(a0, a1);
}

__global__ __launch_bounds__(256) void k_agg64(const u16* __restrict__ H, const int* __restrict__ rowptr,
                                               const int2* __restrict__ csrw, const float* __restrict__ dinv,
                                               const float* __restrict__ bias, u16* __restrict__ out,
                                               int N, int E) {
    const int g = blockIdx.y;
    const int node = blockIdx.x * 4 + (threadIdx.x >> 6);
    if (node >= N) return;
    const int lane = threadIdx.x & 63;
    const u16* h = H + (size_t)g * N * 64;
    const int* rp = rowptr + (size_t)g * (N + 1);
    const int2* cw = csrw + (size_t)g * E;
    const float dn = dinv[g * N + node];
    int e = rp[node];
    const int end = rp[node + 1];
    float a0 = bf2f(h[(size_t)node * 64 + lane]) * dn * dn;
    while (e + 8 <= end) {
        int2 c[8];
#pragma unroll
        for (int j = 0; j < 8; ++j) c[j] = cw[e + j];
        u16 hv[8];
#pragma unroll
        for (int j = 0; j < 8; ++j) hv[j] = h[(size_t)c[j].x * 64 + lane];
#pragma unroll
        for (int j = 0; j < 8; ++j) a0 += bf2f(hv[j]) * __int_as_float(c[j].y);
        e += 8;
    }
    while (e + 2 <= end) {
        int2 c0 = cw[e], c1 = cw[e + 1];
        float h0 = bf2f(h[(size_t)c0.x * 64 + lane]);
        float h1 = bf2f(h[(size_t)c1.x * 64 + lane]);
        a0 += h0 * __int_as_float(c0.y) + h1 * __int_as_float(c1.y);
        e += 2;
    }
    if (e < end) {
        int2 c0 = cw[e];
        a0 += bf2f(h[(size_t)c0.x * 64 + lane]) * __int_as_float(c0.y);
    }
    a0 = fmaxf(a0 + bias[lane], 0.f);
    out[((size_t)g * N + node) * 64 + lane] = f2bf(a0);
}

// ---------------- cluster head ----------------
__global__ __launch_bounds__(256) void k_clus(const u16* __restrict__ v, const float* __restrict__ Wc2,
                                              const float* __restrict__ bc2, void* __restrict__ outv,
                                              size_t out_off, size_t ostride, int N,
                                              const int* __restrict__ flagp) {
    const int g = blockIdx.y;
    const int node = blockIdx.x * 4 + (threadIdx.x >> 6);
    if (node >= N) return;
    const int flag = *flagp;
    const int lane = threadIdx.x & 63;
    float ul = bf2f(v[((size_t)g * N + node) * 64 + lane]);
    float a0 = ul * Wc2[lane * 3 + 0];
    float a1 = ul * Wc2[lane * 3 + 1];
    float a2 = ul * Wc2[lane * 3 + 2];
#pragma unroll
    for (int m = 1; m < 64; m <<= 1) {
        a0 += __shfl_xor(a0, m, 64);
        a1 += __shfl_xor(a1, m, 64);
        a2 += __shfl_xor(a2, m, 64);
    }
    a0 += bc2[0]; a1 += bc2[1]; a2 += bc2[2];
    float mx = fmaxf(a0, fmaxf(a1, a2));
    float e0 = expf(a0 - mx), e1 = expf(a1 - mx), e2 = expf(a2 - mx);
    float inv = 1.f / (e0 + e1 + e2);
    if (lane < 3) {
        float r = (lane == 0) ? e0 : ((lane == 1) ? e1 : e2);
        storex(outv, out_off + (size_t)g * ostride + (size_t)node * 3 + lane, r * inv, flag);
    }
}

// ---------------- launcher ----------------
extern "C" void kernel_launch(void* const* d_in, const int* in_sizes, int n_in,
                              void* d_out, int out_size, void* d_ws, size_t ws_size,
                              hipStream_t stream) {
    const int N = in_sizes[0] / 128;   // 50000
    const int E = in_sizes[1] / 2;     // 800000
    const int* ei0 = (const int*)d_in[1];
    const int* ei1 = (const int*)d_in[3];

    size_t off = 0;
    auto alloc = [&](size_t bytes) -> void* {
        void* p = (char*)d_ws + off;
        off += (bytes + 255) & ~(size_t)255;
        return p;
    };
    int* flag = (int*)alloc(256);
    const int wcnt[12] = {128 * 128, 128, 128 * 64, 64, 64 * 64, 64, 64 * 128, 128, 64 * 64, 64, 64 * 3, 3};
    float* wf[12];
    for (int i = 0; i < 12; ++i) wf[i] = (float*)alloc((size_t)wcnt[i] * 4);
    float* b1f = wf[1]; float* b2f = wf[3]; float* bp1f = wf[5]; float* bp2f = wf[7];
    float* bc1f = wf[9]; float* Wc2f = wf[10]; float* bc2f = wf[11];
    u16* W1T  = (u16*)alloc(128 * 128 * 2);
    u16* W2T  = (u16*)alloc(64 * 128 * 2);
    u16* Wp1T = (u16*)alloc(64 * 64 * 2);
    u16* Wp2T = (u16*)alloc(128 * 64 * 2);
    u16* Wc1T = (u16*)alloc(64 * 64 * 2);

    int* deg    = (int*)alloc((size_t)4 * N * 4);
    int* cursor = deg + 2 * N;
    int* rowptr = (int*)alloc((size_t)2 * (N + 1) * 4);
    int* part   = (int*)alloc(128 * 4);
    float* dinv = (float*)alloc((size_t)2 * N * 4);
    int2* csrw  = (int2*)alloc((size_t)2 * E * 8);
    u16* A1 = (u16*)alloc((size_t)2 * N * 128 * 2);
    u16* H2 = A1;
    u16* Qb = (u16*)alloc((size_t)2 * N * 128 * 2);
    u16* U  = Qb;
    u16* Z  = (u16*)alloc((size_t)2 * N * 64 * 2);
    (void)ws_size; (void)n_in; (void)out_size;

    k_detect<<<1, 64, 0, stream>>>((const u32*)d_in[0], flag);
    ConvJobs jobs;
    for (int i = 0; i < 12; ++i) jobs.j[i] = ConvJob{d_in[4 + i], wf[i], wcnt[i]};
    k_wconv<<<64, 256, 0, stream>>>(jobs, flag);
    TJobs tj;
    tj.j[0] = TJob{wf[0], W1T, 128, 128};
    tj.j[1] = TJob{wf[2], W2T, 128, 64};
    tj.j[2] = TJob{wf[4], Wp1T, 64, 64};
    tj.j[3] = TJob{wf[6], Wp2T, 64, 128};
    tj.j[4] = TJob{wf[8], Wc1T, 64, 64};
    k_wtrans<<<40, 256, 0, stream>>>(tj);

    const int nchunk = (N + 1023) / 1024;
    const dim3 gE((E + 255) / 256, 2);
    const dim3 gS(nchunk, 2);
    const dim3 gM((N + 63) / 64, 2);
    const dim3 gA((N + 3) / 4, 2);

    hipMemsetAsync(deg, 0, (size_t)2 * N * 4, stream);  // cursor written by scan_write
    k_count<<<gE, 256, 0, stream>>>(ei0, ei1, deg, N, E);
    k_scan_part<<<gS, 256, 0, stream>>>(deg, part, N, nchunk);
    k_scan_top<<<1, 128, 0, stream>>>(part, rowptr, N, nchunk);
    k_scan_write<<<gS, 256, 0, stream>>>(deg, part, rowptr, cursor, dinv, N, nchunk);
    k_fill<<<gE, 256, 0, stream>>>(ei0, ei1, cursor, dinv, csrw, N, E);

    // layer 1
    k_mgemm<128, 128, true, false, false, false, false><<<gM, 256, 0, stream>>>(
        d_in[0], d_in[2], 0, W1T, nullptr, A1, 0, (size_t)N * 128, N, flag);
    k_agg128<<<gA, 256, 0, stream>>>((const u32*)A1, rowptr, csrw, dinv, b1f, (u32*)Qb, N, E);
    // layer 2
    k_mgemm<128, 64, false, false, false, false, false><<<gM, 256, 0, stream>>>(
        Qb, Qb, (size_t)N * 128, W2T, nullptr, H2, 0, (size_t)N * 64, N, flag);
    k_agg64<<<gA, 256, 0, stream>>>(H2, rowptr, csrw, dinv, b2f, Z, N, E);

    // instance head
    k_mgemm<64, 64, false, true, true, false, false><<<gM, 256, 0, stream>>>(
        Z, Z, (size_t)N * 64, Wp1T, bp1f, U, 0, (size_t)N * 64, N, flag);
    k_mgemm<64, 128, false, true, false, true, true><<<gM, 256, 0, stream>>>(
        U, U, (size_t)N * 64, Wp2T, bp2f, d_out, 0, (size_t)N * 128, N, flag);
    // cluster head
    k_mgemm<64, 64, false, true, true, false, false><<<gM, 256, 0, stream>>>(
        Z, Z, (size_t)N * 64, Wc1T, bc1f, U, 0, (size_t)N * 64, N, flag);
    k_clus<<<gA, 256, 0, stream>>>(U, Wc2f, bc2f, d_out,
                                   (size_t)2 * N * 128, (size_t)N * 3, N, flag);
}